// Round 1
// baseline (2235.724 us; speedup 1.0000x reference)
//
#include <hip/hip_runtime.h>
#include <cstdint>

#define NTOK 4
#define SEQL 2048
#define EMB 512
#define NH 8
#define HD 64

typedef unsigned int uint32;
typedef unsigned long long uint64;

// ---------------- mask pack: int32 (N,1,S,S) -> bitmask, bit k of word = mask!=0 ----------------
__global__ __launch_bounds__(256) void k_pack_mask(const int* __restrict__ mask,
                                                   uint32* __restrict__ mp) {
    int idx = blockIdx.x * 256 + threadIdx.x;
    int lane = threadIdx.x & 63;
    uint64 b = __ballot(mask[idx] != 0);
    if (lane == 0)  mp[idx >> 5] = (uint32)b;
    if (lane == 32) mp[idx >> 5] = (uint32)(b >> 32);
}

// ---------------- per-head projection: out[n][h][l][d] = sum_e in[n][l][h*64+e] * W[d][e] ------
__global__ __launch_bounds__(256) void k_proj(const float* __restrict__ in,
                                              const float* __restrict__ W,
                                              float* __restrict__ out) {
    __shared__ float xs[64][68];
    __shared__ float ws[64][68];
    const int t  = threadIdx.x;
    const int l0 = blockIdx.x * 64;
    const int n  = blockIdx.y / NH, h = blockIdx.y % NH;

    #pragma unroll
    for (int p = 0; p < 4; ++p) {
        int f = t * 4 + p * 1024;           // covers 64*64 floats
        int r = f >> 6, c = f & 63;
        *(float4*)&ws[r][c] = *(const float4*)&W[f];
        *(float4*)&xs[r][c] = *(const float4*)&in[(size_t)(n * SEQL + l0 + r) * EMB + h * HD + c];
    }
    __syncthreads();

    const int lg = t >> 4, dg = t & 15;     // strided ownership: rows lg+16i, cols dg+16j
    float acc[4][4] = {};
    #pragma unroll
    for (int e = 0; e < 64; e += 4) {
        float4 xv[4], wv[4];
        #pragma unroll
        for (int i = 0; i < 4; ++i) xv[i] = *(const float4*)&xs[lg + 16 * i][e];
        #pragma unroll
        for (int j = 0; j < 4; ++j) wv[j] = *(const float4*)&ws[dg + 16 * j][e];
        #pragma unroll
        for (int i = 0; i < 4; ++i)
            #pragma unroll
            for (int j = 0; j < 4; ++j)
                acc[i][j] += xv[i].x * wv[j].x + xv[i].y * wv[j].y +
                             xv[i].z * wv[j].z + xv[i].w * wv[j].w;
    }
    float* ob = out + (size_t)((n * NH + h) * SEQL + l0) * HD;
    #pragma unroll
    for (int i = 0; i < 4; ++i)
        #pragma unroll
        for (int j = 0; j < 4; ++j)
            ob[(lg + 16 * i) * HD + dg + 16 * j] = acc[i][j];
}

// ---------------- transpose Wout (512x512) so outproj reads are coalesced ----------------------
__global__ __launch_bounds__(256) void k_transpose(const float* __restrict__ W,
                                                   float* __restrict__ WT) {
    __shared__ float tile[32][33];
    int tx = threadIdx.x & 31, ty = threadIdx.x >> 5; // 32 x 8
    int x0 = blockIdx.x * 32, y0 = blockIdx.y * 32;
    #pragma unroll
    for (int i = 0; i < 4; ++i)
        tile[ty + 8 * i][tx] = W[(size_t)(y0 + ty + 8 * i) * EMB + x0 + tx];
    __syncthreads();
    #pragma unroll
    for (int i = 0; i < 4; ++i)
        WT[(size_t)(x0 + ty + 8 * i) * EMB + y0 + tx] = tile[tx][ty + 8 * i];
}

// ---------------- flash attention fp32: Qtile=64, Ktile=64, online softmax ---------------------
__global__ __launch_bounds__(256) void k_attn(const float* __restrict__ qp,
                                              const float* __restrict__ kp,
                                              const float* __restrict__ vp,
                                              const uint64* __restrict__ mp,
                                              float* __restrict__ attn) {
    __shared__ float qs[64][68];
    __shared__ float ks[64][68];
    __shared__ float vs[64][68];
    __shared__ float ps[64][68];
    const int t  = threadIdx.x;
    const int q0 = blockIdx.x * 64;
    const int h  = blockIdx.y, n = blockIdx.z;
    const int lg = t >> 4, sg = t & 15;  // q-rows lg+16i ; cols: S-phase k = sg+16j, PV d = sg*4+j

    const float* qb = qp + (size_t)((n * NH + h) * SEQL + q0) * HD;
    const float* kb = kp + (size_t)(n * NH + h) * SEQL * HD;
    const float* vb = vp + (size_t)(n * NH + h) * SEQL * HD;

    #pragma unroll
    for (int p = 0; p < 4; ++p) {
        int f = t * 4 + p * 1024;
        int r = f >> 6, c = f & 63;
        *(float4*)&qs[r][c] = *(const float4*)&qb[r * HD + c];
    }

    float m[4], lsum[4], o[4][4];
    #pragma unroll
    for (int i = 0; i < 4; ++i) {
        m[i] = -INFINITY; lsum[i] = 0.f;
        #pragma unroll
        for (int j = 0; j < 4; ++j) o[i][j] = 0.f;
    }
    const float sc = 0.044194173824159216f;  // 1/sqrt(512)

    for (int kt = 0; kt < SEQL / 64; ++kt) {
        __syncthreads();  // previous tile's PV reads (and Q load) complete
        #pragma unroll
        for (int p = 0; p < 4; ++p) {
            int f = t * 4 + p * 1024;
            int r = f >> 6, c = f & 63;
            *(float4*)&ks[r][c] = *(const float4*)&kb[(kt * 64 + r) * HD + c];
            *(float4*)&vs[r][c] = *(const float4*)&vb[(kt * 64 + r) * HD + c];
        }
        __syncthreads();

        // S = Q K^T (4x4 per thread)
        float s[4][4] = {};
        #pragma unroll
        for (int e = 0; e < 64; e += 4) {
            float4 qv[4], kv[4];
            #pragma unroll
            for (int i = 0; i < 4; ++i) qv[i] = *(const float4*)&qs[lg + 16 * i][e];
            #pragma unroll
            for (int j = 0; j < 4; ++j) kv[j] = *(const float4*)&ks[sg + 16 * j][e];
            #pragma unroll
            for (int i = 0; i < 4; ++i)
                #pragma unroll
                for (int j = 0; j < 4; ++j)
                    s[i][j] += qv[i].x * kv[j].x + qv[i].y * kv[j].y +
                               qv[i].z * kv[j].z + qv[i].w * kv[j].w;
        }

        // mask + scale
        uint64 mw[4];
        #pragma unroll
        for (int i = 0; i < 4; ++i)
            mw[i] = mp[(size_t)(n * SEQL + q0 + lg + 16 * i) * (SEQL / 64) + kt];
        #pragma unroll
        for (int i = 0; i < 4; ++i)
            #pragma unroll
            for (int j = 0; j < 4; ++j)
                s[i][j] = ((mw[i] >> (sg + 16 * j)) & 1ULL) ? s[i][j] * sc : -1e20f;

        // online softmax per row (16-lane butterfly)
        float pr[4][4];
        #pragma unroll
        for (int i = 0; i < 4; ++i) {
            float rm = fmaxf(fmaxf(s[i][0], s[i][1]), fmaxf(s[i][2], s[i][3]));
            rm = fmaxf(rm, __shfl_xor(rm, 1));
            rm = fmaxf(rm, __shfl_xor(rm, 2));
            rm = fmaxf(rm, __shfl_xor(rm, 4));
            rm = fmaxf(rm, __shfl_xor(rm, 8));
            float mn   = fmaxf(m[i], rm);
            float corr = __expf(m[i] - mn);   // first tile: exp(-inf)=0
            float rs = 0.f;
            #pragma unroll
            for (int j = 0; j < 4; ++j) { pr[i][j] = __expf(s[i][j] - mn); rs += pr[i][j]; }
            rs += __shfl_xor(rs, 1); rs += __shfl_xor(rs, 2);
            rs += __shfl_xor(rs, 4); rs += __shfl_xor(rs, 8);
            lsum[i] = lsum[i] * corr + rs;
            m[i] = mn;
            #pragma unroll
            for (int j = 0; j < 4; ++j) o[i][j] *= corr;
        }

        // P -> LDS
        #pragma unroll
        for (int i = 0; i < 4; ++i)
            #pragma unroll
            for (int j = 0; j < 4; ++j)
                ps[lg + 16 * i][sg + 16 * j] = pr[i][j];
        __syncthreads();

        // O += P V  (d columns sg*4..sg*4+3)
        #pragma unroll
        for (int k = 0; k < 64; k += 4) {
            float4 pv[4], vv[4];
            #pragma unroll
            for (int i = 0; i < 4; ++i)  pv[i]  = *(const float4*)&ps[lg + 16 * i][k];
            #pragma unroll
            for (int kk = 0; kk < 4; ++kk) vv[kk] = *(const float4*)&vs[k + kk][sg * 4];
            #pragma unroll
            for (int i = 0; i < 4; ++i) {
                o[i][0] += pv[i].x * vv[0].x + pv[i].y * vv[1].x + pv[i].z * vv[2].x + pv[i].w * vv[3].x;
                o[i][1] += pv[i].x * vv[0].y + pv[i].y * vv[1].y + pv[i].z * vv[2].y + pv[i].w * vv[3].y;
                o[i][2] += pv[i].x * vv[0].z + pv[i].y * vv[1].z + pv[i].z * vv[2].z + pv[i].w * vv[3].z;
                o[i][3] += pv[i].x * vv[0].w + pv[i].y * vv[1].w + pv[i].z * vv[2].w + pv[i].w * vv[3].w;
            }
        }
    }

    // epilogue: O/l -> attn[n][q][h*64+d]
    float* ab = attn + (size_t)(n * SEQL + q0) * EMB + h * HD;
    #pragma unroll
    for (int i = 0; i < 4; ++i) {
        float inv = 1.0f / lsum[i];
        float4 r;
        r.x = o[i][0] * inv; r.y = o[i][1] * inv; r.z = o[i][2] * inv; r.w = o[i][3] * inv;
        *(float4*)&ab[(size_t)(lg + 16 * i) * EMB + sg * 4] = r;
    }
}

// ---------------- output projection: out[r][c] = sum_e x[r][e]*WT[e][c] + b[c] -----------------
__global__ __launch_bounds__(256) void k_outproj(const float* __restrict__ x,
                                                 const float* __restrict__ WT,
                                                 const float* __restrict__ bias,
                                                 float* __restrict__ out) {
    __shared__ float xs[8][EMB];
    const int t  = threadIdx.x;
    const int r0 = blockIdx.x * 8;
    #pragma unroll
    for (int p = 0; p < 4; ++p) {
        int f = (t + p * 256) * 4;
        int r = f >> 9, c = f & 511;
        *(float4*)&xs[r][c] = *(const float4*)&x[(size_t)(r0 + r) * EMB + c];
    }
    __syncthreads();

    float acc0[8] = {}, acc1[8] = {};
    for (int e = 0; e < EMB; e += 4) {
        float4 xv[8];
        #pragma unroll
        for (int r = 0; r < 8; ++r) xv[r] = *(const float4*)&xs[r][e];
        #pragma unroll
        for (int ee = 0; ee < 4; ++ee) {
            float w0 = WT[(size_t)(e + ee) * EMB + t];
            float w1 = WT[(size_t)(e + ee) * EMB + t + 256];
            #pragma unroll
            for (int r = 0; r < 8; ++r) {
                float xe = (ee == 0) ? xv[r].x : (ee == 1) ? xv[r].y : (ee == 2) ? xv[r].z : xv[r].w;
                acc0[r] += xe * w0;
                acc1[r] += xe * w1;
            }
        }
    }
    float b0 = bias[t], b1 = bias[t + 256];
    #pragma unroll
    for (int r = 0; r < 8; ++r) {
        out[(size_t)(r0 + r) * EMB + t]       = acc0[r] + b0;
        out[(size_t)(r0 + r) * EMB + t + 256] = acc1[r] + b1;
    }
}

extern "C" void kernel_launch(void* const* d_in, const int* in_sizes, int n_in,
                              void* d_out, int out_size, void* d_ws, size_t ws_size,
                              hipStream_t stream) {
    (void)in_sizes; (void)n_in; (void)out_size; (void)ws_size;
    const float* values = (const float*)d_in[0];
    const float* keys   = (const float*)d_in[1];
    const float* query  = (const float*)d_in[2];
    const int*   mask   = (const int*)d_in[3];
    const float* Wv     = (const float*)d_in[4];
    const float* Wk     = (const float*)d_in[5];
    const float* Wq     = (const float*)d_in[6];
    const float* Wout   = (const float*)d_in[7];
    const float* bout   = (const float*)d_in[8];
    float* out = (float*)d_out;

    float* ws = (float*)d_ws;
    const size_t NT = (size_t)NTOK * NH * SEQL * HD;  // 4,194,304 floats
    float* qp = ws;
    float* kp = qp + NT;
    float* vp = kp + NT;
    float* at = vp + NT;
    float* wt = at + NT;
    uint32* mpk = (uint32*)(wt + (size_t)EMB * EMB);  // 2 MB of bitmask

    k_pack_mask<<<(NTOK * SEQL * SEQL) / 256, 256, 0, stream>>>(mask, mpk);
    k_proj<<<dim3(SEQL / 64, NTOK * NH), 256, 0, stream>>>(query,  Wq, qp);
    k_proj<<<dim3(SEQL / 64, NTOK * NH), 256, 0, stream>>>(keys,   Wk, kp);
    k_proj<<<dim3(SEQL / 64, NTOK * NH), 256, 0, stream>>>(values, Wv, vp);
    k_transpose<<<dim3(16, 16), 256, 0, stream>>>(Wout, wt);
    k_attn<<<dim3(SEQL / 64, NH, NTOK), 256, 0, stream>>>(qp, kp, vp, (const uint64*)mpk, at);
    k_outproj<<<(NTOK * SEQL) / 8, 256, 0, stream>>>(at, wt, bout, out);
}

// Round 2
// 427.122 us; speedup vs baseline: 5.2344x; 5.2344x over previous
//
#include <hip/hip_runtime.h>
#include <cstdint>

#define NTOK 4
#define SEQL 2048
#define EMB 512
#define NH 8
#define HD 64

typedef unsigned int uint32;
typedef unsigned long long uint64;
typedef __attribute__((ext_vector_type(8))) short short8;   // 8 bf16 = 4 VGPRs (MFMA A/B frag)
typedef __attribute__((ext_vector_type(4))) float f32x4;    // MFMA C/D frag

__device__ __forceinline__ short f2bf(float f) {
    union { float f; uint32 u; } v; v.f = f;
    uint32 u = v.u;
    u += 0x7fffu + ((u >> 16) & 1u);   // round-nearest-even (finite values)
    return (short)(u >> 16);
}

// ---------------- mask pack: int32 (N,1,S,S) -> bitmask, bit k of word = mask!=0 ----------------
__global__ __launch_bounds__(256) void k_pack_mask(const int* __restrict__ mask,
                                                   uint32* __restrict__ mp) {
    int idx = blockIdx.x * 256 + threadIdx.x;
    int lane = threadIdx.x & 63;
    uint64 b = __ballot(mask[idx] != 0);
    if (lane == 0)  mp[idx >> 5] = (uint32)b;
    if (lane == 32) mp[idx >> 5] = (uint32)(b >> 32);
}

// ---------------- per-head projection -> bf16, optional transposed output ----------------------
// TR=false: out[n][h][l][d]   TR=true: out[n][h][d][l]
template <bool TR>
__global__ __launch_bounds__(256) void k_proj(const float* __restrict__ in,
                                              const float* __restrict__ W,
                                              short* __restrict__ out) {
    __shared__ float xs[64][68];
    __shared__ float ws[64][68];
    __shared__ short os[64][72];
    const int t  = threadIdx.x;
    const int l0 = blockIdx.x * 64;
    const int n  = blockIdx.y / NH, h = blockIdx.y % NH;

    #pragma unroll
    for (int p = 0; p < 4; ++p) {
        int f = t * 4 + p * 1024;           // covers 64*64 floats
        int r = f >> 6, c = f & 63;
        *(float4*)&ws[r][c] = *(const float4*)&W[f];
        *(float4*)&xs[r][c] = *(const float4*)&in[(size_t)(n * SEQL + l0 + r) * EMB + h * HD + c];
    }
    __syncthreads();

    const int lg = t >> 4, dg = t & 15;
    float acc[4][4] = {};
    #pragma unroll
    for (int e = 0; e < 64; e += 4) {
        float4 xv[4], wv[4];
        #pragma unroll
        for (int i = 0; i < 4; ++i) xv[i] = *(const float4*)&xs[lg + 16 * i][e];
        #pragma unroll
        for (int j = 0; j < 4; ++j) wv[j] = *(const float4*)&ws[dg + 16 * j][e];
        #pragma unroll
        for (int i = 0; i < 4; ++i)
            #pragma unroll
            for (int j = 0; j < 4; ++j)
                acc[i][j] += xv[i].x * wv[j].x + xv[i].y * wv[j].y +
                             xv[i].z * wv[j].z + xv[i].w * wv[j].w;
    }
    #pragma unroll
    for (int i = 0; i < 4; ++i)
        #pragma unroll
        for (int j = 0; j < 4; ++j) {
            if (TR) os[dg + 16 * j][lg + 16 * i] = f2bf(acc[i][j]);
            else    os[lg + 16 * i][dg + 16 * j] = f2bf(acc[i][j]);
        }
    __syncthreads();

    const int r = t >> 2, c = (t & 3) * 16;
    size_t base;
    if (TR) base = ((size_t)(n * NH + h) * HD + r) * SEQL + l0 + c;     // rows are d
    else    base = ((size_t)(n * NH + h) * SEQL + l0 + r) * HD + c;     // rows are l
    *(short8*)&out[base]     = *(const short8*)&os[r][c];
    *(short8*)&out[base + 8] = *(const short8*)&os[r][c + 8];
}

// ---------------- transpose Wout (512x512) ------------------------------------------------------
__global__ __launch_bounds__(256) void k_transpose(const float* __restrict__ W,
                                                   float* __restrict__ WT) {
    __shared__ float tile[32][33];
    int tx = threadIdx.x & 31, ty = threadIdx.x >> 5;
    int x0 = blockIdx.x * 32, y0 = blockIdx.y * 32;
    #pragma unroll
    for (int i = 0; i < 4; ++i)
        tile[ty + 8 * i][tx] = W[(size_t)(y0 + ty + 8 * i) * EMB + x0 + tx];
    __syncthreads();
    #pragma unroll
    for (int i = 0; i < 4; ++i)
        WT[(size_t)(x0 + ty + 8 * i) * EMB + y0 + tx] = tile[tx][ty + 8 * i];
}

// ---------------- flash attention, bf16 MFMA 16x16x32, fp32 accumulate --------------------------
// qp,kp: bf16 [n][h][l][64]; vp: bf16 [n][h][64][l]; out at: fp32 [n][l][h*64+d]
__global__ __launch_bounds__(256, 4) void k_attn(const short* __restrict__ qp,
                                                 const short* __restrict__ kp,
                                                 const short* __restrict__ vp,
                                                 const uint64* __restrict__ mp,
                                                 float* __restrict__ attn) {
    __shared__ short qs[64][72];
    __shared__ short ks[64][72];
    __shared__ short vt[64][72];      // vt[d][k] within tile
    __shared__ short ps[4][16][72];   // per-wave P tile (16 q x 64 k)
    __shared__ uint64 ms[64];

    const int t    = threadIdx.x;
    const int w    = t >> 6;          // wave 0..3, owns q-rows [w*16, w*16+16)
    const int lane = t & 63;
    const int lg16 = lane >> 4;       // 0..3
    const int l15  = lane & 15;
    const int q0   = blockIdx.x * 64;
    const int h    = blockIdx.y, n = blockIdx.z;

    const short* qg = qp + ((size_t)(n * NH + h) * SEQL + q0) * HD;
    const short* kg = kp + (size_t)(n * NH + h) * SEQL * HD;
    const short* vg = vp + (size_t)(n * NH + h) * HD * SEQL;

    // stage Q tile (64x64 bf16)
    {
        const int r = t >> 2, c = (t & 3) * 16;
        *(short8*)&qs[r][c]     = *(const short8*)&qg[r * HD + c];
        *(short8*)&qs[r][c + 8] = *(const short8*)&qg[r * HD + c + 8];
    }
    __syncthreads();

    // Q A-fragments (persist whole kernel): row = l15 of wave slab, cols lg16*8 + i + 32*kstep
    short8 qa[2];
    #pragma unroll
    for (int kstp = 0; kstp < 2; ++kstp)
        qa[kstp] = *(const short8*)&qs[w * 16 + l15][lg16 * 8 + 32 * kstp];

    float m[4], lsum[4];
    f32x4 o[4];
    #pragma unroll
    for (int r = 0; r < 4; ++r) {
        m[r] = -INFINITY; lsum[r] = 0.f;
        o[r] = (f32x4){0.f, 0.f, 0.f, 0.f};
    }
    const float sc = 0.044194173824159216f;  // 1/sqrt(512)

    for (int kt = 0; kt < SEQL / 64; ++kt) {
        __syncthreads();   // prior tile's ks/vt reads complete
        {
            const int r = t >> 2, c = (t & 3) * 16;
            *(short8*)&ks[r][c]     = *(const short8*)&kg[(kt * 64 + r) * HD + c];
            *(short8*)&ks[r][c + 8] = *(const short8*)&kg[(kt * 64 + r) * HD + c + 8];
            *(short8*)&vt[r][c]     = *(const short8*)&vg[(size_t)r * SEQL + kt * 64 + c];
            *(short8*)&vt[r][c + 8] = *(const short8*)&vg[(size_t)r * SEQL + kt * 64 + c + 8];
            if (t < 64) ms[t] = mp[(size_t)(n * SEQL + q0 + t) * (SEQL / 64) + kt];
        }
        __syncthreads();

        // ---- S = Q K^T : 4 stiles x 2 ksteps ----
        f32x4 s[4];
        #pragma unroll
        for (int st = 0; st < 4; ++st) {
            s[st] = (f32x4){0.f, 0.f, 0.f, 0.f};
            #pragma unroll
            for (int kstp = 0; kstp < 2; ++kstp) {
                short8 kb = *(const short8*)&ks[st * 16 + l15][lg16 * 8 + 32 * kstp];
                s[st] = __builtin_amdgcn_mfma_f32_16x16x32_bf16(qa[kstp], kb, s[st], 0, 0, 0);
            }
        }

        // ---- mask + scale; rows = lg16*4 + r ----
        uint64 mw[4];
        #pragma unroll
        for (int r = 0; r < 4; ++r)
            mw[r] = ms[w * 16 + lg16 * 4 + r];
        #pragma unroll
        for (int st = 0; st < 4; ++st)
            #pragma unroll
            for (int r = 0; r < 4; ++r)
                s[st][r] = ((mw[r] >> (st * 16 + l15)) & 1ULL) ? s[st][r] * sc : -1e20f;

        // ---- online softmax (row reduce across l15 via shfl_xor 1,2,4,8) ----
        float pr[4][4];  // [stile][r]
        #pragma unroll
        for (int r = 0; r < 4; ++r) {
            float rm = fmaxf(fmaxf(s[0][r], s[1][r]), fmaxf(s[2][r], s[3][r]));
            rm = fmaxf(rm, __shfl_xor(rm, 1));
            rm = fmaxf(rm, __shfl_xor(rm, 2));
            rm = fmaxf(rm, __shfl_xor(rm, 4));
            rm = fmaxf(rm, __shfl_xor(rm, 8));
            float mn   = fmaxf(m[r], rm);
            float corr = __expf(m[r] - mn);
            float rs = 0.f;
            #pragma unroll
            for (int st = 0; st < 4; ++st) { pr[st][r] = __expf(s[st][r] - mn); rs += pr[st][r]; }
            rs += __shfl_xor(rs, 1); rs += __shfl_xor(rs, 2);
            rs += __shfl_xor(rs, 4); rs += __shfl_xor(rs, 8);
            lsum[r] = lsum[r] * corr + rs;
            m[r] = mn;
            #pragma unroll
            for (int dt = 0; dt < 4; ++dt) o[dt][r] *= corr;
        }

        // ---- P -> per-wave LDS (bf16); wave-local, no barrier needed ----
        #pragma unroll
        for (int st = 0; st < 4; ++st)
            #pragma unroll
            for (int r = 0; r < 4; ++r)
                ps[w][lg16 * 4 + r][st * 16 + l15] = f2bf(pr[st][r]);

        // ---- O += P V : 4 dtiles x 2 ksteps ----
        short8 pa[2];
        #pragma unroll
        for (int kstp = 0; kstp < 2; ++kstp)
            pa[kstp] = *(const short8*)&ps[w][l15][lg16 * 8 + 32 * kstp];
        #pragma unroll
        for (int dt = 0; dt < 4; ++dt) {
            #pragma unroll
            for (int kstp = 0; kstp < 2; ++kstp) {
                short8 vb = *(const short8*)&vt[dt * 16 + l15][lg16 * 8 + 32 * kstp];
                o[dt] = __builtin_amdgcn_mfma_f32_16x16x32_bf16(pa[kstp], vb, o[dt], 0, 0, 0);
            }
        }
    }

    // ---- epilogue: at[n][q][h*64+d] = O / lsum ----
    float* ab = attn + ((size_t)(n * SEQL) + q0 + w * 16) * EMB + h * HD;
    #pragma unroll
    for (int r = 0; r < 4; ++r) {
        float inv = 1.0f / lsum[r];
        int row = lg16 * 4 + r;
        #pragma unroll
        for (int dt = 0; dt < 4; ++dt)
            ab[(size_t)row * EMB + dt * 16 + l15] = o[dt][r] * inv;
    }
}

// ---------------- output projection: out[r][c] = sum_e x[r][e]*WT[e][c] + b[c] -----------------
__global__ __launch_bounds__(256) void k_outproj(const float* __restrict__ x,
                                                 const float* __restrict__ WT,
                                                 const float* __restrict__ bias,
                                                 float* __restrict__ out) {
    __shared__ float xs[8][EMB];
    const int t  = threadIdx.x;
    const int r0 = blockIdx.x * 8;
    #pragma unroll
    for (int p = 0; p < 4; ++p) {
        int f = (t + p * 256) * 4;
        int r = f >> 9, c = f & 511;
        *(float4*)&xs[r][c] = *(const float4*)&x[(size_t)(r0 + r) * EMB + c];
    }
    __syncthreads();

    float acc0[8] = {}, acc1[8] = {};
    for (int e = 0; e < EMB; e += 4) {
        float4 xv[8];
        #pragma unroll
        for (int r = 0; r < 8; ++r) xv[r] = *(const float4*)&xs[r][e];
        #pragma unroll
        for (int ee = 0; ee < 4; ++ee) {
            float w0 = WT[(size_t)(e + ee) * EMB + t];
            float w1 = WT[(size_t)(e + ee) * EMB + t + 256];
            #pragma unroll
            for (int r = 0; r < 8; ++r) {
                float xe = (ee == 0) ? xv[r].x : (ee == 1) ? xv[r].y : (ee == 2) ? xv[r].z : xv[r].w;
                acc0[r] += xe * w0;
                acc1[r] += xe * w1;
            }
        }
    }
    float b0 = bias[t], b1 = bias[t + 256];
    #pragma unroll
    for (int r = 0; r < 8; ++r) {
        out[(size_t)(r0 + r) * EMB + t]       = acc0[r] + b0;
        out[(size_t)(r0 + r) * EMB + t + 256] = acc1[r] + b1;
    }
}

extern "C" void kernel_launch(void* const* d_in, const int* in_sizes, int n_in,
                              void* d_out, int out_size, void* d_ws, size_t ws_size,
                              hipStream_t stream) {
    (void)in_sizes; (void)n_in; (void)out_size; (void)ws_size;
    const float* values = (const float*)d_in[0];
    const float* keys   = (const float*)d_in[1];
    const float* query  = (const float*)d_in[2];
    const int*   mask   = (const int*)d_in[3];
    const float* Wv     = (const float*)d_in[4];
    const float* Wk     = (const float*)d_in[5];
    const float* Wq     = (const float*)d_in[6];
    const float* Wout   = (const float*)d_in[7];
    const float* bout   = (const float*)d_in[8];
    float* out = (float*)d_out;

    const size_t NT = (size_t)NTOK * NH * SEQL * HD;  // 4,194,304 elements
    short* qp = (short*)d_ws;
    short* kp = qp + NT;
    short* vp = kp + NT;
    float* at = (float*)(vp + NT);
    float* wt = at + NT;
    uint32* mpk = (uint32*)(wt + (size_t)EMB * EMB);

    k_pack_mask<<<(NTOK * SEQL * SEQL) / 256, 256, 0, stream>>>(mask, mpk);
    k_proj<false><<<dim3(SEQL / 64, NTOK * NH), 256, 0, stream>>>(query,  Wq, qp);
    k_proj<false><<<dim3(SEQL / 64, NTOK * NH), 256, 0, stream>>>(keys,   Wk, kp);
    k_proj<true ><<<dim3(SEQL / 64, NTOK * NH), 256, 0, stream>>>(values, Wv, vp);
    k_transpose<<<dim3(16, 16), 256, 0, stream>>>(Wout, wt);
    k_attn<<<dim3(SEQL / 64, NH, NTOK), 256, 0, stream>>>(qp, kp, vp, (const uint64*)mpk, at);
    k_outproj<<<(NTOK * SEQL) / 8, 256, 0, stream>>>(at, wt, bout, out);
}

// Round 6
// 379.649 us; speedup vs baseline: 5.8889x; 1.1250x over previous
//
#include <hip/hip_runtime.h>
#include <cstdint>

#define NTOK 4
#define SEQL 2048
#define EMB 512
#define NH 8
#define HD 64

typedef unsigned int uint32;
typedef unsigned long long uint64;
typedef __attribute__((ext_vector_type(8))) short short8;
typedef __attribute__((ext_vector_type(16))) float f32x16;

union frag_u { uint32 u[4]; short8 s; };

// fp32 -> bf16 round-nearest-even (round-2-proven numerics)
__device__ __forceinline__ unsigned short f2bf(float f) {
    union { float f; uint32 u; } v; v.f = f;
    uint32 u = v.u;
    u += 0x7fffu + ((u >> 16) & 1u);
    return (unsigned short)(u >> 16);
}

__device__ __forceinline__ uint32 pkbf16(float a, float b) {
    return ((uint32)f2bf(b) << 16) | (uint32)f2bf(a);
}

// ---------------- mask pack: int32 (N,1,S,S) -> bitmask ----------------------------------------
__global__ __launch_bounds__(256) void k_pack_mask(const int* __restrict__ mask,
                                                   uint32* __restrict__ mp) {
    int idx = blockIdx.x * 256 + threadIdx.x;
    int lane = threadIdx.x & 63;
    uint64 b = __ballot(mask[idx] != 0);
    if (lane == 0)  mp[idx >> 5] = (uint32)b;
    if (lane == 32) mp[idx >> 5] = (uint32)(b >> 32);
}

// ---------------- per-head projection -> bf16, optional transposed output ----------------------
template <bool TR>
__global__ __launch_bounds__(256) void k_proj(const float* __restrict__ in,
                                              const float* __restrict__ W,
                                              short* __restrict__ out) {
    __shared__ float xs[64][68];
    __shared__ float ws[64][68];
    __shared__ short os[64][72];
    const int t  = threadIdx.x;
    const int l0 = blockIdx.x * 64;
    const int n  = blockIdx.y / NH, h = blockIdx.y % NH;

    #pragma unroll
    for (int p = 0; p < 4; ++p) {
        int f = t * 4 + p * 1024;
        int r = f >> 6, c = f & 63;
        *(float4*)&ws[r][c] = *(const float4*)&W[f];
        *(float4*)&xs[r][c] = *(const float4*)&in[(size_t)(n * SEQL + l0 + r) * EMB + h * HD + c];
    }
    __syncthreads();

    const int lg = t >> 4, dg = t & 15;
    float acc[4][4] = {};
    #pragma unroll
    for (int e = 0; e < 64; e += 4) {
        float4 xv[4], wv[4];
        #pragma unroll
        for (int i = 0; i < 4; ++i) xv[i] = *(const float4*)&xs[lg + 16 * i][e];
        #pragma unroll
        for (int j = 0; j < 4; ++j) wv[j] = *(const float4*)&ws[dg + 16 * j][e];
        #pragma unroll
        for (int i = 0; i < 4; ++i)
            #pragma unroll
            for (int j = 0; j < 4; ++j)
                acc[i][j] += xv[i].x * wv[j].x + xv[i].y * wv[j].y +
                             xv[i].z * wv[j].z + xv[i].w * wv[j].w;
    }
    #pragma unroll
    for (int i = 0; i < 4; ++i)
        #pragma unroll
        for (int j = 0; j < 4; ++j) {
            short sv = (short)f2bf(acc[i][j]);
            if (TR) os[dg + 16 * j][lg + 16 * i] = sv;
            else    os[lg + 16 * i][dg + 16 * j] = sv;
        }
    __syncthreads();

    const int r = t >> 2, c = (t & 3) * 16;
    size_t base;
    if (TR) base = ((size_t)(n * NH + h) * HD + r) * SEQL + l0 + c;
    else    base = ((size_t)(n * NH + h) * SEQL + l0 + r) * HD + c;
    *(short8*)&out[base]     = *(const short8*)&os[r][c];
    *(short8*)&out[base + 8] = *(const short8*)&os[r][c + 8];
}

// ---------------- transpose Wout (512x512) ------------------------------------------------------
__global__ __launch_bounds__(256) void k_transpose(const float* __restrict__ W,
                                                   float* __restrict__ WT) {
    __shared__ float tile[32][33];
    int tx = threadIdx.x & 31, ty = threadIdx.x >> 5;
    int x0 = blockIdx.x * 32, y0 = blockIdx.y * 32;
    #pragma unroll
    for (int i = 0; i < 4; ++i)
        tile[ty + 8 * i][tx] = W[(size_t)(y0 + ty + 8 * i) * EMB + x0 + tx];
    __syncthreads();
    #pragma unroll
    for (int i = 0; i < 4; ++i)
        WT[(size_t)(x0 + ty + 8 * i) * EMB + y0 + tx] = tile[tx][ty + 8 * i];
}

// ---------------- staging: 64x64 bf16 tile via global_load_lds, XOR-preswizzled src -------------
__device__ __forceinline__ void stage64x64(const short* __restrict__ gbase, int rstride,
                                           short* ldst, int t) {
    #pragma unroll
    for (int p = 0; p < 2; ++p) {
        int i = p * 256 + t;
        int row = i >> 3, c = i & 7;
        const short* src = gbase + (size_t)row * rstride + ((c ^ (row & 7)) << 3);
        short* dst = ldst + ((i & ~63) << 3);
        __builtin_amdgcn_global_load_lds((const __attribute__((address_space(1))) uint32*)src,
                                         (__attribute__((address_space(3))) uint32*)dst,
                                         16, 0, 0);
    }
}

// ---------------- flash attention: swapped 32x32 MFMA, in-register softmax, fp32 out ------------
// Cross-half exchange is done ONLY via __shfl_xor(.,32) (unambiguous semantics).
// qp,kp: bf16 [n][h][l][64]; vp: bf16 [n][h][d][l]; out at: fp32 [n][l][h*64+d]
__global__ __launch_bounds__(256, 2) void k_attn(const short* __restrict__ qp,
                                                 const short* __restrict__ kp,
                                                 const short* __restrict__ vp,
                                                 const uint64* __restrict__ mp,
                                                 float* __restrict__ attn) {
    __shared__ short lds[2][2][64 * 64];   // [buf][K/V][row*64 + swizzled col]

    const int t    = threadIdx.x;
    const int lane = t & 63;
    const int w    = t >> 6;
    const int hi   = lane >> 5;
    const int l31  = lane & 31;

    int d  = (blockIdx.z * NH + blockIdx.y) * (SEQL / 128) + blockIdx.x;   // 0..511
    int lb = (d & 7) * 64 + (d >> 3);
    const int qt = lb & 15;
    const int h  = (lb >> 4) & 7;
    const int n  = lb >> 7;
    const int q0 = qt * 128;

    const short* qg = qp + (size_t)(n * NH + h) * SEQL * HD;
    const short* kg = kp + (size_t)(n * NH + h) * SEQL * HD;
    const short* vg = vp + (size_t)(n * NH + h) * HD * SEQL;

    const int qrow = q0 + w * 32 + l31;

    short8 qf[4];
    #pragma unroll
    for (int st = 0; st < 4; ++st)
        qf[st] = *(const short8*)&qg[(size_t)qrow * HD + st * 16 + hi * 8];

    f32x16 o0 = (f32x16)0.0f, o1 = (f32x16)0.0f;
    float mrun = -3.0e38f, lsum = 0.0f;
    const float c2 = 0.06376303932318478f;   // (1/sqrt(512)) * log2(e)

    stage64x64(kg, HD, &lds[0][0][0], t);
    stage64x64(vg, SEQL, &lds[0][1][0], t);
    __syncthreads();

    int cur = 0;
    #pragma unroll 1
    for (int kt = 0; kt < SEQL / 64; ++kt) {
        uint64 mw = mp[((size_t)(n * SEQL) + qrow) * 32 + kt];
        if (kt < SEQL / 64 - 1) {
            stage64x64(kg + (kt + 1) * 64 * HD, HD, &lds[cur ^ 1][0][0], t);
            stage64x64(vg + (kt + 1) * 64, SEQL, &lds[cur ^ 1][1][0], t);
        }
        const short* ks = &lds[cur][0][0];
        const short* vs = &lds[cur][1][0];

        // ---- S^T = K Q^T : D[key][q], col=l31=q, row key=(r&3)+8*(r>>2)+4*hi (+32*sub) ----
        f32x16 s0 = (f32x16)0.0f, s1 = (f32x16)0.0f;
        #pragma unroll
        for (int st = 0; st < 4; ++st) {
            int ch = ((2 * st + hi) ^ (l31 & 7)) << 3;
            short8 kf0 = *(const short8*)&ks[l31 * 64 + ch];
            s0 = __builtin_amdgcn_mfma_f32_32x32x16_bf16(kf0, qf[st], s0, 0, 0, 0);
            short8 kf1 = *(const short8*)&ks[(32 + l31) * 64 + ch];
            s1 = __builtin_amdgcn_mfma_f32_32x32x16_bf16(kf1, qf[st], s1, 0, 0, 0);
        }

        // ---- mask ----
        uint32 m0w = (uint32)(mw >> (4 * hi));
        uint32 m1w = (uint32)(mw >> (32 + 4 * hi));
        #pragma unroll
        for (int g = 0; g < 4; ++g)
            #pragma unroll
            for (int b = 0; b < 4; ++b) {
                int r = g * 4 + b;
                s0[r] = ((m0w >> (8 * g + b)) & 1u) ? s0[r] : -1e20f;
                s1[r] = ((m1w >> (8 * g + b)) & 1u) ? s1[r] : -1e20f;
            }

        // ---- row max (own 32 values, then cross-half via shfl_xor 32) ----
        float mx[8];
        #pragma unroll
        for (int i = 0; i < 8; ++i)
            mx[i] = fmaxf(fmaxf(s0[i], s0[i + 8]), fmaxf(s1[i], s1[i + 8]));
        float rm = fmaxf(fmaxf(fmaxf(mx[0], mx[1]), fmaxf(mx[2], mx[3])),
                         fmaxf(fmaxf(mx[4], mx[5]), fmaxf(mx[6], mx[7])));
        rm = fmaxf(rm, __shfl_xor(rm, 32));
        float mn   = fmaxf(mrun, rm);
        float mnc  = mn * c2;
        float corr = __builtin_amdgcn_exp2f(mrun * c2 - mnc);

        // ---- P = exp2(s*c2 - mnc) ----
        #pragma unroll
        for (int r = 0; r < 16; ++r) {
            s0[r] = __builtin_amdgcn_exp2f(__builtin_fmaf(s0[r], c2, -mnc));
            s1[r] = __builtin_amdgcn_exp2f(__builtin_fmaf(s1[r], c2, -mnc));
        }

        // ---- row sum + cross-half ----
        float sm[8];
        #pragma unroll
        for (int i = 0; i < 8; ++i)
            sm[i] = (s0[i] + s0[i + 8]) + (s1[i] + s1[i + 8]);
        float rs = ((sm[0] + sm[1]) + (sm[2] + sm[3])) + ((sm[4] + sm[5]) + (sm[6] + sm[7]));
        rs += __shfl_xor(rs, 32);
        lsum = lsum * corr + rs;
        mrun = mn;
        #pragma unroll
        for (int r = 0; r < 16; ++r) { o0[r] *= corr; o1[r] *= corr; }

        // ---- P -> bf16 B-fragments via pkbf16 + shfl_xor(32) + select ----
        // lane(hi,l31) reg j must hold P^T[key = base + 8*hi + j][q=l31].
        // Own regs hold keys {4*hi + b + 8*g}; partner half holds the complementary 4-key groups.
        frag_u pf[4];
        #pragma unroll
        for (int half = 0; half < 2; ++half) {
            const f32x16& sv = half ? s1 : s0;
            #pragma unroll
            for (int grp = 0; grp < 2; ++grp) {
                // grp 0: regs 0..7 (keys base+0..15), grp 1: regs 8..15 (keys base+16..31)
                uint32 x0 = pkbf16(sv[8 * grp + 0], sv[8 * grp + 1]);   // keys 4hi+0,1 (+8*2grp)
                uint32 x1 = pkbf16(sv[8 * grp + 2], sv[8 * grp + 3]);   // keys 4hi+2,3
                uint32 y0 = pkbf16(sv[8 * grp + 4], sv[8 * grp + 5]);   // keys 4hi+8,9
                uint32 y1 = pkbf16(sv[8 * grp + 6], sv[8 * grp + 7]);   // keys 4hi+10,11
                uint32 sx0 = __shfl_xor(x0, 32), sx1 = __shfl_xor(x1, 32);
                uint32 sy0 = __shfl_xor(y0, 32), sy1 = __shfl_xor(y1, 32);
                frag_u& f = pf[half * 2 + grp];
                f.u[0] = hi ? sy0 : x0;   // keys base+{0,1} / base+{8,9}
                f.u[1] = hi ? sy1 : x1;   // keys base+{2,3} / base+{10,11}
                f.u[2] = hi ? y0  : sx0;  // keys base+{4,5} / base+{12,13}
                f.u[3] = hi ? y1  : sx1;  // keys base+{6,7} / base+{14,15}
            }
        }

        // ---- O^T += V^T P^T ----
        #pragma unroll
        for (int k4 = 0; k4 < 4; ++k4) {
            int ch = ((2 * k4 + hi) ^ (l31 & 7)) << 3;
            short8 vf0 = *(const short8*)&vs[l31 * 64 + ch];
            o0 = __builtin_amdgcn_mfma_f32_32x32x16_bf16(vf0, pf[k4].s, o0, 0, 0, 0);
            short8 vf1 = *(const short8*)&vs[(32 + l31) * 64 + ch];
            o1 = __builtin_amdgcn_mfma_f32_32x32x16_bf16(vf1, pf[k4].s, o1, 0, 0, 0);
        }

        __syncthreads();
        cur ^= 1;
    }

    // ---- epilogue: fp32 at[n][qrow][h*64+d]; d = 32*dt + 8*g + 4*hi + j ----
    float inv = 1.0f / lsum;
    float* ab = attn + ((size_t)(n * SEQL) + qrow) * EMB + h * HD;
    #pragma unroll
    for (int dt = 0; dt < 2; ++dt)
        #pragma unroll
        for (int g = 0; g < 4; ++g) {
            float4 v;
            v.x = (dt ? o1[4 * g + 0] : o0[4 * g + 0]) * inv;
            v.y = (dt ? o1[4 * g + 1] : o0[4 * g + 1]) * inv;
            v.z = (dt ? o1[4 * g + 2] : o0[4 * g + 2]) * inv;
            v.w = (dt ? o1[4 * g + 3] : o0[4 * g + 3]) * inv;
            *(float4*)&ab[dt * 32 + 8 * g + 4 * hi] = v;
        }
}

// ---------------- output projection (round-2-proven fp32): out = x @ WT + b ---------------------
__global__ __launch_bounds__(256) void k_outproj(const float* __restrict__ x,
                                                 const float* __restrict__ WT,
                                                 const float* __restrict__ bias,
                                                 float* __restrict__ out) {
    __shared__ float xs[8][EMB];
    const int t  = threadIdx.x;
    const int r0 = blockIdx.x * 8;
    #pragma unroll
    for (int p = 0; p < 4; ++p) {
        int f = (t + p * 256) * 4;
        int r = f >> 9, c = f & 511;
        *(float4*)&xs[r][c] = *(const float4*)&x[(size_t)(r0 + r) * EMB + c];
    }
    __syncthreads();

    float acc0[8] = {}, acc1[8] = {};
    for (int e = 0; e < EMB; e += 4) {
        float4 xv[8];
        #pragma unroll
        for (int r = 0; r < 8; ++r) xv[r] = *(const float4*)&xs[r][e];
        #pragma unroll
        for (int ee = 0; ee < 4; ++ee) {
            float w0 = WT[(size_t)(e + ee) * EMB + t];
            float w1 = WT[(size_t)(e + ee) * EMB + t + 256];
            #pragma unroll
            for (int r = 0; r < 8; ++r) {
                float xe = (ee == 0) ? xv[r].x : (ee == 1) ? xv[r].y : (ee == 2) ? xv[r].z : xv[r].w;
                acc0[r] += xe * w0;
                acc1[r] += xe * w1;
            }
        }
    }
    float b0 = bias[t], b1 = bias[t + 256];
    #pragma unroll
    for (int r = 0; r < 8; ++r) {
        out[(size_t)(r0 + r) * EMB + t]       = acc0[r] + b0;
        out[(size_t)(r0 + r) * EMB + t + 256] = acc1[r] + b1;
    }
}

extern "C" void kernel_launch(void* const* d_in, const int* in_sizes, int n_in,
                              void* d_out, int out_size, void* d_ws, size_t ws_size,
                              hipStream_t stream) {
    (void)in_sizes; (void)n_in; (void)out_size; (void)ws_size;
    const float* values = (const float*)d_in[0];
    const float* keys   = (const float*)d_in[1];
    const float* query  = (const float*)d_in[2];
    const int*   mask   = (const int*)d_in[3];
    const float* Wv     = (const float*)d_in[4];
    const float* Wk     = (const float*)d_in[5];
    const float* Wq     = (const float*)d_in[6];
    const float* Wout   = (const float*)d_in[7];
    const float* bout   = (const float*)d_in[8];
    float* out = (float*)d_out;

    const size_t NT = (size_t)NTOK * NH * SEQL * HD;   // 4,194,304
    short* qp = (short*)d_ws;
    short* kp = qp + NT;
    short* vp = kp + NT;
    float* at = (float*)(vp + NT);
    float* wt = at + NT;
    uint32* mpk = (uint32*)(wt + (size_t)EMB * EMB);

    k_pack_mask<<<(NTOK * SEQL * SEQL) / 256, 256, 0, stream>>>(mask, mpk);
    k_proj<false><<<dim3(SEQL / 64, NTOK * NH), 256, 0, stream>>>(query,  Wq, qp);
    k_proj<false><<<dim3(SEQL / 64, NTOK * NH), 256, 0, stream>>>(keys,   Wk, kp);
    k_proj<true ><<<dim3(SEQL / 64, NTOK * NH), 256, 0, stream>>>(values, Wv, vp);
    k_transpose<<<dim3(16, 16), 256, 0, stream>>>(Wout, wt);
    k_attn<<<dim3(SEQL / 128, NH, NTOK), 256, 0, stream>>>(qp, kp, vp, (const uint64*)mpk, at);
    k_outproj<<<(NTOK * SEQL) / 8, 256, 0, stream>>>(at, wt, bout, out);
}